// Round 17
// baseline (918.117 us; speedup 1.0000x reference)
//
#include <hip/hip_runtime.h>

typedef unsigned short u16;
typedef __attribute__((ext_vector_type(8))) short bfx8;   // 8 bf16 in 4 VGPRs
typedef __attribute__((ext_vector_type(4))) float f32x4;
typedef __attribute__((ext_vector_type(4))) unsigned short u16x4;

__device__ __forceinline__ float bf2f(u16 u){ return __builtin_bit_cast(float, (unsigned)u << 16); }
__device__ __forceinline__ u16 f2bf(float f){
  unsigned u = __builtin_bit_cast(unsigned, f);
  return (u16)((u + 0x7fffu + ((u >> 16) & 1u)) >> 16);
}

__device__ __forceinline__ void gload_lds16(const void* g, void* l){
  __builtin_amdgcn_global_load_lds((const __attribute__((address_space(1))) void*)g,
                                   (__attribute__((address_space(3))) void*)l, 16, 0, 0);
}

// ---------------- fp32 -> bf16 convert ----------------
__global__ __launch_bounds__(256) void cvt_kernel(const float* __restrict__ in, u16* __restrict__ out, int n4){
  int i = blockIdx.x * 256 + threadIdx.x;
  if (i >= n4) return;
  f32x4 v = *(const f32x4*)&in[(long)i * 4];
  u16x4 o = { f2bf(v[0]), f2bf(v[1]), f2bf(v[2]), f2bf(v[3]) };
  *(u16x4*)&out[(long)i * 4] = o;
}

// ---------------- 256^2 8-phase GEMM (round-13 proven best: 295us, MfmaUtil 43.4) ----------------
// Phase-head ds_reads; B-fragments hoisted at phase 0; deep staging k0:B(u+1) k1:A1(u+1)
// k3:A0(u+2)+vmcnt(2). Swizzle colbyte ^= (row&7)<<4 on source + ds_read. Do NOT manually
// pipeline the ds_reads (r12 same-reg and r14 renamed both measured slower).
template<int F32OUT>
__global__ __launch_bounds__(512, 2)
void gemm256(const u16* __restrict__ A, const u16* __restrict__ W,
             void* __restrict__ out0, void* __restrict__ out1,
             int K, int ld0, int ld1, int nsplit)
{
  __shared__ __align__(16) u16 SA[2][16384];
  __shared__ __align__(16) u16 SB[2][16384];
  const int tid = threadIdx.x;
  const int wid = tid >> 6, lane = tid & 63;
  const int wr = wid >> 2, wc = wid & 3;
  const int bm = blockIdx.x, bn = blockIdx.y;
  const int rr = lane & 15, kg = lane >> 4;
  const int NT = K >> 6;

  const int srow = tid >> 3;
  const int ssw = ((tid & 7) * 16) ^ ((srow & 7) << 4);
  const u16* gA = A + ((long)bm * 256 + srow) * K + (ssw >> 1);
  const u16* gB = W + ((long)bn * 256 + srow) * K + (ssw >> 1);
  const long r64 = (long)64 * K;
  const int dst = tid * 8;

#define STAGE_A(t, ht) { const u16* s_ = gA + (long)(ht) * 2 * r64 + ((t) << 6); \
    gload_lds16(s_,       &SA[(t) & 1][(ht) * 8192 + dst]); \
    gload_lds16(s_ + r64, &SA[(t) & 1][(ht) * 8192 + 4096 + dst]); }
#define STAGE_B(t, ht) { const u16* s_ = gB + (long)(ht) * 2 * r64 + ((t) << 6); \
    gload_lds16(s_,       &SB[(t) & 1][(ht) * 8192 + dst]); \
    gload_lds16(s_ + r64, &SB[(t) & 1][(ht) * 8192 + 4096 + dst]); }

  const int swr = (rr & 7) << 4;
  const int ca0 = ((kg * 16) ^ swr) >> 1;        // ks=0 col (elems, swizzled)
  const int ca1 = ((64 + kg * 16) ^ swr) >> 1;   // ks=1
  int bA[8], bB[4];
#pragma unroll
  for (int j = 0; j < 8; j++) bA[j] = ((2 * j + wr) * 16 + rr) * 64;
#pragma unroll
  for (int i = 0; i < 4; i++) bB[i] = ((4 * i + wc) * 16 + rr) * 64;

  f32x4 acc[8][4] = {};

  // prologue: tile0 fully + A0(1); vmcnt(2) leaves A0(1) flying
  STAGE_A(0, 0); STAGE_A(0, 1); STAGE_B(0, 0); STAGE_B(0, 1);
  if (NT > 1) STAGE_A(1, 0);
  asm volatile("s_waitcnt vmcnt(2)" ::: "memory");
  asm volatile("s_barrier" ::: "memory");

  for (int u = 0; u < NT; ++u){
    const int p = u & 1;
    bfx8 bf[4][2];
#pragma unroll
    for (int k = 0; k < 4; ++k){
      bfx8 af[2][2];
#pragma unroll
      for (int jj = 0; jj < 2; jj++){
        const int base = bA[2 * k + jj];
        af[jj][0] = *(const bfx8*)&SA[p][base + ca0];
        af[jj][1] = *(const bfx8*)&SA[p][base + ca1];
      }
      if (k == 0){
#pragma unroll
        for (int i = 0; i < 4; i++){
          bf[i][0] = *(const bfx8*)&SB[p][bB[i] + ca0];
          bf[i][1] = *(const bfx8*)&SB[p][bB[i] + ca1];
        }
        if (u + 1 < NT) { STAGE_B(u + 1, 0); STAGE_B(u + 1, 1); }   // B slots free: last read P0 of tile u-1
      }
      else if (k == 1) { if (u + 1 < NT) STAGE_A(u + 1, 1); }       // A1 slot free: last read P3 of tile u-1
      else if (k == 3) {
        if (u + 2 < NT)      { STAGE_A(u + 2, 0); asm volatile("s_waitcnt vmcnt(2)" ::: "memory"); }
        else if (u + 1 < NT) { asm volatile("s_waitcnt vmcnt(0)" ::: "memory"); }
      }
      asm volatile("s_barrier" ::: "memory");
      __builtin_amdgcn_s_setprio(1);
#pragma unroll
      for (int jj = 0; jj < 2; jj++)
#pragma unroll
        for (int i = 0; i < 4; i++){
          acc[2 * k + jj][i] = __builtin_amdgcn_mfma_f32_16x16x32_bf16(af[jj][0], bf[i][0], acc[2 * k + jj][i], 0, 0, 0);
          acc[2 * k + jj][i] = __builtin_amdgcn_mfma_f32_16x16x32_bf16(af[jj][1], bf[i][1], acc[2 * k + jj][i], 0, 0, 0);
        }
      __builtin_amdgcn_s_setprio(0);
    }
  }
#undef STAGE_A
#undef STAGE_B

  int bn2 = bn; void* op = out0; int ldo = ld0;
  if (bn >= nsplit){ bn2 = bn - nsplit; op = out1; ldo = ld1; }
  const int r4b = (lane >> 4) * 4;
#pragma unroll
  for (int j = 0; j < 8; j++)
#pragma unroll
    for (int i = 0; i < 4; i++)
#pragma unroll
      for (int r4 = 0; r4 < 4; r4++){
        long row = (long)bm * 256 + (2 * j + wr) * 16 + r4b + r4;
        long col = (long)bn2 * 256 + (4 * i + wc) * 16 + rr;
        long idx = row * ldo + col;
        if (F32OUT) ((float*)op)[idx] = acc[j][i][r4];
        else        ((u16*)op)[idx]  = f2bf(acc[j][i][r4]);
      }
}

// ---------------- dt: fp32 skinny GEMM + softplus/clip; also emits hsb (bf16 of hs) ----------------
__global__ __launch_bounds__(256) void dt_kernel(const float* __restrict__ hs, const float* __restrict__ w,
                                                 const float* __restrict__ dt_bias, float* __restrict__ dtp,
                                                 u16* __restrict__ hsb){
  __shared__ float hsS[32][66];
  __shared__ float wS[64][66];
  const int tid = threadIdx.x;
  const int j = tid & 63, rgrp = tid >> 6;
  const long row0 = (long)blockIdx.x * 32;
  const int srow = tid >> 3, sc0 = (tid & 7) * 8;
  const int wrow = tid >> 2, wc0 = (tid & 3) * 16;
  const float* hsg = hs + (row0 + srow) * 2048 + sc0;
  const float* wg  = w + (long)(8448 + wrow) * 2048 + wc0;

  f32x4 acc[8] = {};
  for (int k0 = 0; k0 < 2048; k0 += 64){
    f32x4 va = *(const f32x4*)&hsg[k0];
    f32x4 vb = *(const f32x4*)&hsg[k0 + 4];
    *(f32x4*)&hsS[srow][sc0]     = va;
    *(f32x4*)&hsS[srow][sc0 + 4] = vb;
    u16x4 oa = { f2bf(va[0]), f2bf(va[1]), f2bf(va[2]), f2bf(va[3]) };
    u16x4 ob = { f2bf(vb[0]), f2bf(vb[1]), f2bf(vb[2]), f2bf(vb[3]) };
    *(u16x4*)&hsb[(row0 + srow) * 2048 + k0 + sc0]     = oa;
    *(u16x4*)&hsb[(row0 + srow) * 2048 + k0 + sc0 + 4] = ob;
#pragma unroll
    for (int q = 0; q < 4; q++)
      *(f32x4*)&wS[wrow][wc0 + q * 4] = *(const f32x4*)&wg[k0 + q * 4];
    __syncthreads();
#pragma unroll
    for (int kk = 0; kk < 64; kk += 4){
      f32x4 wv = *(const f32x4*)&wS[j][kk];
#pragma unroll
      for (int r = 0; r < 8; r++){
        f32x4 hv = *(const f32x4*)&hsS[rgrp * 8 + r][kk];
        acc[r] += hv * wv;
      }
    }
    __syncthreads();
  }
  float bias = dt_bias[j];
#pragma unroll
  for (int r = 0; r < 8; r++){
    float x = acc[r][0] + acc[r][1] + acc[r][2] + acc[r][3] + bias;
    float sp = (x > 20.f) ? x : log1pf(expf(x));
    sp = fminf(fmaxf(sp, 0.f), 100.f);
    dtp[(row0 + rgrp * 8 + r) * 64 + j] = sp;
  }
}

// ---------------- per (b,h,chunk): Adt cumsum (fp32) ----------------
__global__ __launch_bounds__(64) void acum_kernel(const float* __restrict__ dtp, const float* __restrict__ A_log,
                                                  float* __restrict__ acum, float* __restrict__ suma){
  int bid = blockIdx.x;                 // ((b*64+h)*16+c)
  int c = bid & 15, h = (bid >> 4) & 63, b = bid >> 10;
  int lane = threadIdx.x;
  float Ah = -expf(A_log[h]);
  long base = ((long)(b * 4096 + c * 256)) * 64 + h;
  float v[4]; float s = 0.f;
#pragma unroll
  for (int i = 0; i < 4; i++){ float adt = dtp[base + (lane * 4 + i) * 64] * Ah; s += adt; v[i] = s; }
  float tot = s, run = s;
  for (int off = 1; off < 64; off <<= 1){ float u = __shfl_up(run, off); if (lane >= off) run += u; }
  float excl = run - tot;
  long ob = (long)bid * 256 + lane * 4;
#pragma unroll
  for (int i = 0; i < 4; i++) acum[ob + i] = excl + v[i];
  if (lane == 63) suma[bid] = run;
}

// ---------------- depthwise conv + bias + silu + split: 8 l-positions/block, 11-row window ----------------
__global__ __launch_bounds__(256) void conv_kernel(const u16* __restrict__ xbc, const float* __restrict__ cw,
                                                   const float* __restrict__ cb,
                                                   u16* __restrict__ xact,
                                                   u16* __restrict__ bmat, u16* __restrict__ cmat){
  int pb = blockIdx.x;                  // b*512 + l8
  int l0 = (pb & 511) * 8;
  long pos0 = ((long)(pb >> 9) << 12) + l0;
  for (int cg = threadIdx.x; cg < 544; cg += 256){
    int ch = cg * 8;
    f32x4 cwv[8];
#pragma unroll
    for (int t = 0; t < 8; t++) cwv[t] = *(const f32x4*)&cw[(ch + t) * 4];
    float cbv[8];
#pragma unroll
    for (int t = 0; t < 8; t++) cbv[t] = cb[ch + t];
    bfx8 rr[11];
    bfx8 zz = {};
    rr[0] = (l0 >= 3) ? *(const bfx8*)&xbc[(pos0 - 3) * 4352 + ch] : zz;
    rr[1] = (l0 >= 2) ? *(const bfx8*)&xbc[(pos0 - 2) * 4352 + ch] : zz;
    rr[2] = (l0 >= 1) ? *(const bfx8*)&xbc[(pos0 - 1) * 4352 + ch] : zz;
#pragma unroll
    for (int q = 0; q < 8; q++) rr[3 + q] = *(const bfx8*)&xbc[(pos0 + q) * 4352 + ch];
#pragma unroll
    for (int li = 0; li < 8; li++){
      bfx8 o;
#pragma unroll
      for (int t = 0; t < 8; t++){
        float a = cbv[t] + cwv[t][0] * bf2f((u16)rr[li][t])     + cwv[t][1] * bf2f((u16)rr[li + 1][t])
                         + cwv[t][2] * bf2f((u16)rr[li + 2][t]) + cwv[t][3] * bf2f((u16)rr[li + 3][t]);
        float val = a / (1.f + expf(-a));
        o[t] = (short)f2bf(val);
      }
      long pos = pos0 + li;
      if (ch < 4096)      *(bfx8*)&xact[pos * 4096 + ch] = o;
      else if (ch < 4224) *(bfx8*)&bmat[pos * 128 + ch - 4096] = o;
      else                *(bfx8*)&cmat[pos * 128 + ch - 4224] = o;
    }
  }
}

// ---------------- bmat[b*4096+l][128] -> bmatT[b][n][4096] ----------------
__global__ __launch_bounds__(256) void bt_transpose(const u16* __restrict__ bmat, u16* __restrict__ bmatT){
  __shared__ u16 T[128 * 136];
  int bx = blockIdx.x;                  // b*32 + ltile
  int b = bx >> 5, lt = bx & 31;
  int l0 = lt * 128;
  int tid = threadIdx.x;
  for (int idx = tid; idx < 2048; idx += 256){
    int lrow = idx >> 4, ns = (idx & 15) * 8;
    *(bfx8*)&T[lrow * 136 + ns] = *(const bfx8*)&bmat[((long)b * 4096 + l0 + lrow) * 128 + ns];
  }
  __syncthreads();
  for (int idx = tid; idx < 2048; idx += 256){
    int nrow = idx >> 4, ls = (idx & 15) * 8;
    bfx8 o;
#pragma unroll
    for (int j = 0; j < 8; j++) o[j] = (short)T[(ls + j) * 136 + nrow];
    *(bfx8*)&bmatT[(long)b * 524288 + (long)nrow * 4096 + l0 + ls] = o;
  }
}

// ---------------- per (b,c): G = C @ B^T (256x256, fp32) -- head-independent, computed once ----------------
__global__ __launch_bounds__(256) void cbt_kernel(const u16* __restrict__ cmat, const u16* __restrict__ bmat,
                                                  float* __restrict__ G){
  int bid = blockIdx.x;                 // (b*16+c)*4 + ss
  int ss = bid & 3, bc = bid >> 2;
  int b = bc >> 4, c = bc & 15;
  long rowbase = (long)b * 4096 + c * 256;
  int tid = threadIdx.x, wid = tid >> 6, lane = tid & 63;
  int rr = lane & 15, ko = (lane >> 4) * 8;
  f32x4 acc[4][4] = {};
#pragma unroll
  for (int kk = 0; kk < 4; kk++){
    bfx8 cf[4], bf[4];
#pragma unroll
    for (int lt = 0; lt < 4; lt++) cf[lt] = *(const bfx8*)&cmat[(rowbase + wid * 64 + lt * 16 + rr) * 128 + kk * 32 + ko];
#pragma unroll
    for (int st = 0; st < 4; st++) bf[st] = *(const bfx8*)&bmat[(rowbase + ss * 64 + st * 16 + rr) * 128 + kk * 32 + ko];
#pragma unroll
    for (int lt = 0; lt < 4; lt++)
#pragma unroll
      for (int st = 0; st < 4; st++)
        acc[lt][st] = __builtin_amdgcn_mfma_f32_16x16x32_bf16(cf[lt], bf[st], acc[lt][st], 0, 0, 0);
  }
  long gb2 = (long)bc * 65536;
#pragma unroll
  for (int lt = 0; lt < 4; lt++)
#pragma unroll
    for (int st = 0; st < 4; st++)
#pragma unroll
      for (int r4 = 0; r4 < 4; r4++)
        G[gb2 + (long)(wid * 64 + lt * 16 + (lane >> 4) * 4 + r4) * 256 + ss * 64 + st * 16 + rr] = acc[lt][st][r4];
}

// ---------------- per (b,c,h): chunk end-state E = (X*dt*decay)^T @ B  (bf16 out) ----------------
__global__ __launch_bounds__(256, 4) void states_kernel(const u16* __restrict__ xact, const u16* __restrict__ bmatT,
                                                        const float* __restrict__ acum, const float* __restrict__ suma,
                                                        const float* __restrict__ dtp, u16* __restrict__ stR){
  __shared__ __align__(16) u16 XdT[64 * 264];
  __shared__ float fac[256];
  int bid = blockIdx.x;                 // ((b*16+c)*64+h)
  int h = bid & 63, c = (bid >> 6) & 15, b = bid >> 10;
  int tid = threadIdx.x;
  long rowbase = (long)b * 4096 + c * 256;
  long aco = ((long)((b * 64 + h) * 16 + c)) * 256;
  float sA = suma[(b * 64 + h) * 16 + c];
  fac[tid] = dtp[(rowbase + tid) * 64 + h] * expf(sA - acum[aco + tid]);
  __syncthreads();
  char* xb = (char*)XdT;
  for (int idx = tid; idx < 2048; idx += 256){
    int l = idx >> 3, ps = (idx & 7) * 8;
    int key = (idx & 7) << 4;
    bfx8 xv = *(const bfx8*)&xact[(rowbase + l) * 4096 + h * 64 + ps];
#pragma unroll
    for (int j = 0; j < 8; j++)
      *(u16*)(xb + ((((ps + j) * 264 + l) * 2) ^ key)) = f2bf(bf2f((u16)xv[j]) * fac[l]);
  }
  __syncthreads();
  int wid = tid >> 6, lane = tid & 63;
  int rr = lane & 15, ko = (lane >> 4) * 8;
  const u16* btb = bmatT + (long)b * 524288 + c * 256;
  const int arow = wid * 16 + rr;
  const int akey = ((arow >> 3) & 7) << 4;
  f32x4 acc[8] = {};
#pragma unroll
  for (int ks = 0; ks < 8; ks++){
    bfx8 a = *(const bfx8*)(xb + (((arow * 264 + ks * 32 + ko) * 2) ^ akey));
#pragma unroll
    for (int nt = 0; nt < 8; nt++){
      bfx8 bb = *(const bfx8*)&btb[(long)(nt * 16 + rr) * 4096 + ks * 32 + ko];
      acc[nt] = __builtin_amdgcn_mfma_f32_16x16x32_bf16(a, bb, acc[nt], 0, 0, 0);
    }
  }
  long ob = (long)bid * 8192;
#pragma unroll
  for (int nt = 0; nt < 8; nt++)
#pragma unroll
    for (int r4 = 0; r4 < 4; r4++){
      int p = wid * 16 + (lane >> 4) * 4 + r4;
      stR[ob + p * 128 + nt * 16 + rr] = f2bf(acc[nt][r4]);
    }
}

// ---------------- inter-chunk scan: in-place E -> R (prev_states), bf16; 1024 blocks ----------------
__global__ __launch_bounds__(256) void scan_kernel(u16* stR, const float* __restrict__ suma){
  int g = blockIdx.x;                   // ((b*64+h)*8 + slice)
  int s = g & 7, bh = g >> 3;
  int b = bh >> 6, h = bh & 63;
  int tid = threadIdx.x;
  long off0 = (long)s * 1024 + tid * 4;
  f32x4 R = {};
  for (int c = 0; c < 16; c++){
    long base = ((long)((b * 16 + c) * 64 + h)) * 8192 + off0;
    float sc = expf(suma[(b * 64 + h) * 16 + c]);
    u16x4 e4 = *(const u16x4*)&stR[base];
    u16x4 o = { f2bf(R[0]), f2bf(R[1]), f2bf(R[2]), f2bf(R[3]) };
    *(u16x4*)&stR[base] = o;
#pragma unroll
    for (int t = 0; t < 4; t++) R[t] = sc * R[t] + bf2f(e4[t]);
  }
}

// ---------------- per (b,c,h): Y = (G ∘ L) @ Xdt + exp(Acum)*(C @ R^T) + x*D ----------------
// Wave w owns strips {w, 7-w} (32 rows each): balanced causal work (18 lt-sp units per
// wave vs 8..32 in the contiguous mapping -- critical path 32 -> 18).
__global__ __launch_bounds__(256, 4) void ydiag_kernel(const u16* __restrict__ cmat, const float* __restrict__ G,
                                                       const u16* xact,
                                                       const u16* __restrict__ rbuf, const float* __restrict__ acum,
                                                       const float* __restrict__ dtp,
                                                       const float* __restrict__ Dv, u16* ybuf){
  __shared__ __align__(16) u16 XdTq[64 * 72];
  __shared__ float acL[256];
  __shared__ float dtl[256];
  int bid = blockIdx.x;                 // ((b*16+c)*64+h)
  int h = bid & 63, c = (bid >> 6) & 15, b = bid >> 10;
  int tid = threadIdx.x, wid = tid >> 6, lane = tid & 63;
  long rowbase = (long)b * 4096 + c * 256;
  long aco = ((long)((b * 64 + h) * 16 + c)) * 256;
  acL[tid] = acum[aco + tid];
  dtl[tid] = dtp[(rowbase + tid) * 64 + h];
  __syncthreads();

  int rr = lane & 15, ko = (lane >> 4) * 8;
  int lrow0[4];
#pragma unroll
  for (int lt = 0; lt < 4; lt++)
    lrow0[lt] = (lt < 2) ? (32 * wid + lt * 16) : (32 * (7 - wid) + (lt - 2) * 16);

  f32x4 acc[4][4] = {};

  // Y_off = C @ R^T, scaled by exp(acum[l])
  long rb = (long)bid * 8192;
#pragma unroll
  for (int kk = 0; kk < 4; kk++){
    bfx8 cf[4];
#pragma unroll
    for (int lt = 0; lt < 4; lt++)
      cf[lt] = *(const bfx8*)&cmat[(rowbase + lrow0[lt] + rr) * 128 + kk * 32 + ko];
#pragma unroll
    for (int pt = 0; pt < 4; pt++){
      bfx8 bb = *(const bfx8*)&rbuf[rb + (pt * 16 + rr) * 128 + kk * 32 + ko];
#pragma unroll
      for (int lt = 0; lt < 4; lt++) acc[lt][pt] = __builtin_amdgcn_mfma_f32_16x16x32_bf16(cf[lt], bb, acc[lt][pt], 0, 0, 0);
    }
  }
#pragma unroll
  for (int lt = 0; lt < 4; lt++)
#pragma unroll
    for (int r4 = 0; r4 < 4; r4++){
      float e = expf(acL[lrow0[lt] + (lane >> 4) * 4 + r4]);
#pragma unroll
      for (int pt = 0; pt < 4; pt++) acc[lt][pt][r4] *= e;
    }

  char* xqb = (char*)XdTq;
  const long gb2 = (long)((b * 16 + c)) * 65536;
  for (int q = 0; q < 4; q++){
    __syncthreads();
    for (int idx = tid; idx < 512; idx += 256){
      int lq = idx >> 3, ps = (idx & 7) * 8;
      int key = (idx & 7) << 4;
      int l = q * 64 + lq;
      bfx8 xv = *(const bfx8*)&xact[(rowbase + l) * 4096 + h * 64 + ps];
#pragma unroll
      for (int j = 0; j < 8; j++)
        *(u16*)(xqb + ((((ps + j) * 72 + lq) * 2) ^ key)) = f2bf(bf2f((u16)xv[j]) * dtl[l]);
    }
    __syncthreads();
#pragma unroll
    for (int sub = 0; sub < 2; sub++){
      int sp = q * 2 + sub;
      bool doA = (sp <= wid), doB = (sp <= 7 - wid);   // wave-uniform
      if (!doA && !doB) continue;
      int s0 = sp * 32;
#pragma unroll
      for (int lt = 0; lt < 4; lt++){
        if (lt < 2 ? !doA : !doB) continue;
        int lrow = lrow0[lt] + rr;
        float eL = acL[lrow];
        f32x4 g0 = *(const f32x4*)&G[gb2 + (long)lrow * 256 + s0 + ko];
        f32x4 g1 = *(const f32x4*)&G[gb2 + (long)lrow * 256 + s0 + ko + 4];
        bfx8 a1;
#pragma unroll
        for (int j = 0; j < 4; j++){
          int s = s0 + ko + j;
          float sc = (s <= lrow) ? expf(eL - acL[s]) : 0.f;
          a1[j] = (short)f2bf(g0[j] * sc);
        }
#pragma unroll
        for (int j = 0; j < 4; j++){
          int s = s0 + ko + 4 + j;
          float sc = (s <= lrow) ? expf(eL - acL[s]) : 0.f;
          a1[4 + j] = (short)f2bf(g1[j] * sc);
        }
#pragma unroll
        for (int pt = 0; pt < 4; pt++){
          int prow = pt * 16 + rr;
          bfx8 bb = *(const bfx8*)(xqb + (((prow * 72 + sub * 32 + ko) * 2) ^ (((prow >> 3) & 7) << 4)));
          acc[lt][pt] = __builtin_amdgcn_mfma_f32_16x16x32_bf16(a1, bb, acc[lt][pt], 0, 0, 0);
        }
      }
    }
  }
  float Dh = Dv[h];
#pragma unroll
  for (int lt = 0; lt < 4; lt++)
#pragma unroll
    for (int pt = 0; pt < 4; pt++)
#pragma unroll
      for (int r4 = 0; r4 < 4; r4++){
        int lrow = lrow0[lt] + (lane >> 4) * 4 + r4;
        int pcol = pt * 16 + rr;
        long gi = (rowbase + lrow) * 4096 + h * 64 + pcol;
        ybuf[gi] = f2bf(acc[lt][pt][r4] + bf2f(xact[gi]) * Dh);
      }
}

// ---------------- RMSNorm + silu(z) gate (may write in place over ybuf) ----------------
__global__ __launch_bounds__(256) void rms_kernel(const u16* ybuf, const u16* zbuf,
                                                  const float* __restrict__ norm_w, u16* ynorm){
  __shared__ float red[4];
  long row = blockIdx.x;
  int tid = threadIdx.x;
  long yb = row * 4096 + tid * 16;
  bfx8 v0 = *(const bfx8*)&ybuf[yb];
  bfx8 v1 = *(const bfx8*)&ybuf[yb + 8];
  float vals[16];
#pragma unroll
  for (int t = 0; t < 8; t++){ vals[t] = bf2f((u16)v0[t]); vals[8 + t] = bf2f((u16)v1[t]); }
  float ss = 0.f;
#pragma unroll
  for (int t = 0; t < 16; t++) ss += vals[t] * vals[t];
#pragma unroll
  for (int off = 32; off >= 1; off >>= 1) ss += __shfl_xor(ss, off);
  if ((tid & 63) == 0) red[tid >> 6] = ss;
  __syncthreads();
  float rs = rsqrtf((red[0] + red[1] + red[2] + red[3]) * (1.f / 4096.f) + 1e-5f);
  bfx8 z0 = *(const bfx8*)&zbuf[yb];
  bfx8 z1 = *(const bfx8*)&zbuf[yb + 8];
  bfx8 o0, o1;
#pragma unroll
  for (int t = 0; t < 16; t++){
    float zv = bf2f((u16)(t < 8 ? z0[t] : z1[t - 8]));
    float g = zv / (1.f + expf(-zv));
    u16 r = f2bf(vals[t] * rs * norm_w[tid * 16 + t] * g);
    if (t < 8) o0[t] = (short)r; else o1[t - 8] = (short)r;
  }
  *(bfx8*)&ynorm[yb] = o0;
  *(bfx8*)&ynorm[yb + 8] = o1;
}

extern "C" void kernel_launch(void* const* d_in, const int* in_sizes, int n_in,
                              void* d_out, int out_size, void* d_ws, size_t ws_size,
                              hipStream_t stream){
  const float* hs   = (const float*)d_in[0];
  const float* inw  = (const float*)d_in[1];
  const float* cw   = (const float*)d_in[2];
  const float* cb   = (const float*)d_in[3];
  const float* dtb  = (const float*)d_in[4];
  const float* alog = (const float*)d_in[5];
  const float* Dv   = (const float*)d_in[6];
  const float* nw   = (const float*)d_in[7];
  const float* outw = (const float*)d_in[8];

  const size_t REQ = 147857408ULL;
  if (ws_size < REQ){
    hipMemsetAsync(d_out, 0x42, (size_t)out_size * 4, stream);
    return;
  }
  char* ws = (char*)d_ws;
  u16*   hsb  = (u16*)  (ws + 0L);             // 33,554,432   (written by dt; dead after gemm1)
  u16*   wbi  = (u16*)  (ws + 33554432L);      // 34,603,008   (dead after gemm1)
  u16*   xbc  = (u16*)  (ws + 68157440L);      // 71,303,168   (dead after conv)
  u16*   xact = (u16*)  (ws + 0L);             // 67,108,864   (overlays hsb+wbi; = ybuf = ynorm)
  u16*   stR  = (u16*)  (ws + 68157440L);      // 33,554,432   (overlays xbc)
  u16*   wbo  = (u16*)  (ws + 101711872L);     // 16,777,216   (overlays xbc)
  u16*   bmatT= (u16*)  (ws + 118489088L);     //  2,097,152   (overlays xbc)
  float* Gbuf = (float*)(ws + 120586240L);     //  8,388,608   (overlays xbc tail; ends 128,974,848)
  float* dtp  = (float*)(ws + 139460608L);     //  2,097,152
  float* acum = (float*)(ws + 141557760L);     //  2,097,152
  float* suma = (float*)(ws + 143654912L);     //      8,192
  u16*   bmat = (u16*)  (ws + 143663104L);     //  2,097,152
  u16*   cmat = (u16*)  (ws + 145760256L);     //  2,097,152  (end = 147,857,408)
  u16*   zbuf = (u16*)  d_out;                 // 67,108,864 = exactly out_size*4

  cvt_kernel<<<16896, 256, 0, stream>>>(inw, wbi, 4325376);
  dt_kernel<<<256, 256, 0, stream>>>(hs, inw, dtb, dtp, hsb);              // dtp + hsb (bf16 hs)
  gemm256<0><<<dim3(32, 33), 512, 0, stream>>>(hsb, wbi, zbuf, xbc, 2048, 4096, 4352, 16);
  acum_kernel<<<2048, 64, 0, stream>>>(dtp, alog, acum, suma);
  conv_kernel<<<1024, 256, 0, stream>>>(xbc, cw, cb, xact, bmat, cmat);    // xact over dead hsb+wbi
  cvt_kernel<<<8192, 256, 0, stream>>>(outw, wbo, 2097152);                // wbo over dead xbc
  bt_transpose<<<64, 256, 0, stream>>>(bmat, bmatT);
  cbt_kernel<<<128, 256, 0, stream>>>(cmat, bmat, Gbuf);                   // G = C@B^T per (b,c)
  states_kernel<<<2048, 256, 0, stream>>>(xact, bmatT, acum, suma, dtp, stR);
  scan_kernel<<<1024, 256, 0, stream>>>(stR, suma);
  ydiag_kernel<<<2048, 256, 0, stream>>>(cmat, Gbuf, xact, stR, acum, dtp, Dv, xact);  // in-place Y
  rms_kernel<<<8192, 256, 0, stream>>>(xact, zbuf, nw, xact);                           // in-place norm
  gemm256<1><<<dim3(32, 8), 512, 0, stream>>>(xact, wbo, d_out, d_out, 4096, 2048, 2048, 999);
}

// Round 18
// 902.617 us; speedup vs baseline: 1.0172x; 1.0172x over previous
//
#include <hip/hip_runtime.h>

typedef unsigned short u16;
typedef __attribute__((ext_vector_type(8))) short bfx8;   // 8 bf16 in 4 VGPRs
typedef __attribute__((ext_vector_type(4))) float f32x4;
typedef __attribute__((ext_vector_type(4))) unsigned short u16x4;

__device__ __forceinline__ float bf2f(u16 u){ return __builtin_bit_cast(float, (unsigned)u << 16); }
__device__ __forceinline__ u16 f2bf(float f){
  unsigned u = __builtin_bit_cast(unsigned, f);
  return (u16)((u + 0x7fffu + ((u >> 16) & 1u)) >> 16);
}

__device__ __forceinline__ void gload_lds16(const void* g, void* l){
  __builtin_amdgcn_global_load_lds((const __attribute__((address_space(1))) void*)g,
                                   (__attribute__((address_space(3))) void*)l, 16, 0, 0);
}

// ---------------- fp32 -> bf16 convert (single) ----------------
__global__ __launch_bounds__(256) void cvt_kernel(const float* __restrict__ in, u16* __restrict__ out, int n4){
  int i = blockIdx.x * 256 + threadIdx.x;
  if (i >= n4) return;
  f32x4 v = *(const f32x4*)&in[(long)i * 4];
  u16x4 o = { f2bf(v[0]), f2bf(v[1]), f2bf(v[2]), f2bf(v[3]) };
  *(u16x4*)&out[(long)i * 4] = o;
}

// ---------------- fp32 -> bf16 convert (two arrays, one launch) ----------------
__global__ __launch_bounds__(256) void cvt2_kernel(const float* __restrict__ a, u16* __restrict__ oa, int na4,
                                                   const float* __restrict__ b2, u16* __restrict__ ob, int nb4){
  int i = blockIdx.x * 256 + threadIdx.x;
  const float* src; u16* dst; int idx;
  if (i < na4){ src = a; dst = oa; idx = i; }
  else { idx = i - na4; if (idx >= nb4) return; src = b2; dst = ob; }
  f32x4 v = *(const f32x4*)&src[(long)idx * 4];
  u16x4 o = { f2bf(v[0]), f2bf(v[1]), f2bf(v[2]), f2bf(v[3]) };
  *(u16x4*)&dst[(long)idx * 4] = o;
}

// ---------------- 256^2 8-phase GEMM (round-13 proven best: 295us, MfmaUtil 43.4) ----------------
// Phase-head ds_reads; B-fragments hoisted at phase 0; deep staging k0:B(u+1) k1:A1(u+1)
// k3:A0(u+2)+vmcnt(2). Swizzle colbyte ^= (row&7)<<4 on source + ds_read. Do NOT manually
// pipeline the ds_reads (r12 same-reg and r14 renamed both measured slower).
template<int F32OUT>
__global__ __launch_bounds__(512, 2)
void gemm256(const u16* __restrict__ A, const u16* __restrict__ W,
             void* __restrict__ out0, void* __restrict__ out1,
             int K, int ld0, int ld1, int nsplit)
{
  __shared__ __align__(16) u16 SA[2][16384];
  __shared__ __align__(16) u16 SB[2][16384];
  const int tid = threadIdx.x;
  const int wid = tid >> 6, lane = tid & 63;
  const int wr = wid >> 2, wc = wid & 3;
  const int bm = blockIdx.x, bn = blockIdx.y;
  const int rr = lane & 15, kg = lane >> 4;
  const int NT = K >> 6;

  const int srow = tid >> 3;
  const int ssw = ((tid & 7) * 16) ^ ((srow & 7) << 4);
  const u16* gA = A + ((long)bm * 256 + srow) * K + (ssw >> 1);
  const u16* gB = W + ((long)bn * 256 + srow) * K + (ssw >> 1);
  const long r64 = (long)64 * K;
  const int dst = tid * 8;

#define STAGE_A(t, ht) { const u16* s_ = gA + (long)(ht) * 2 * r64 + ((t) << 6); \
    gload_lds16(s_,       &SA[(t) & 1][(ht) * 8192 + dst]); \
    gload_lds16(s_ + r64, &SA[(t) & 1][(ht) * 8192 + 4096 + dst]); }
#define STAGE_B(t, ht) { const u16* s_ = gB + (long)(ht) * 2 * r64 + ((t) << 6); \
    gload_lds16(s_,       &SB[(t) & 1][(ht) * 8192 + dst]); \
    gload_lds16(s_ + r64, &SB[(t) & 1][(ht) * 8192 + 4096 + dst]); }

  const int swr = (rr & 7) << 4;
  const int ca0 = ((kg * 16) ^ swr) >> 1;        // ks=0 col (elems, swizzled)
  const int ca1 = ((64 + kg * 16) ^ swr) >> 1;   // ks=1
  int bA[8], bB[4];
#pragma unroll
  for (int j = 0; j < 8; j++) bA[j] = ((2 * j + wr) * 16 + rr) * 64;
#pragma unroll
  for (int i = 0; i < 4; i++) bB[i] = ((4 * i + wc) * 16 + rr) * 64;

  f32x4 acc[8][4] = {};

  // prologue: tile0 fully + A0(1); vmcnt(2) leaves A0(1) flying
  STAGE_A(0, 0); STAGE_A(0, 1); STAGE_B(0, 0); STAGE_B(0, 1);
  if (NT > 1) STAGE_A(1, 0);
  asm volatile("s_waitcnt vmcnt(2)" ::: "memory");
  asm volatile("s_barrier" ::: "memory");

  for (int u = 0; u < NT; ++u){
    const int p = u & 1;
    bfx8 bf[4][2];
#pragma unroll
    for (int k = 0; k < 4; ++k){
      bfx8 af[2][2];
#pragma unroll
      for (int jj = 0; jj < 2; jj++){
        const int base = bA[2 * k + jj];
        af[jj][0] = *(const bfx8*)&SA[p][base + ca0];
        af[jj][1] = *(const bfx8*)&SA[p][base + ca1];
      }
      if (k == 0){
#pragma unroll
        for (int i = 0; i < 4; i++){
          bf[i][0] = *(const bfx8*)&SB[p][bB[i] + ca0];
          bf[i][1] = *(const bfx8*)&SB[p][bB[i] + ca1];
        }
        if (u + 1 < NT) { STAGE_B(u + 1, 0); STAGE_B(u + 1, 1); }   // B slots free: last read P0 of tile u-1
      }
      else if (k == 1) { if (u + 1 < NT) STAGE_A(u + 1, 1); }       // A1 slot free: last read P3 of tile u-1
      else if (k == 3) {
        if (u + 2 < NT)      { STAGE_A(u + 2, 0); asm volatile("s_waitcnt vmcnt(2)" ::: "memory"); }
        else if (u + 1 < NT) { asm volatile("s_waitcnt vmcnt(0)" ::: "memory"); }
      }
      asm volatile("s_barrier" ::: "memory");
      __builtin_amdgcn_s_setprio(1);
#pragma unroll
      for (int jj = 0; jj < 2; jj++)
#pragma unroll
        for (int i = 0; i < 4; i++){
          acc[2 * k + jj][i] = __builtin_amdgcn_mfma_f32_16x16x32_bf16(af[jj][0], bf[i][0], acc[2 * k + jj][i], 0, 0, 0);
          acc[2 * k + jj][i] = __builtin_amdgcn_mfma_f32_16x16x32_bf16(af[jj][1], bf[i][1], acc[2 * k + jj][i], 0, 0, 0);
        }
      __builtin_amdgcn_s_setprio(0);
    }
  }
#undef STAGE_A
#undef STAGE_B

  int bn2 = bn; void* op = out0; int ldo = ld0;
  if (bn >= nsplit){ bn2 = bn - nsplit; op = out1; ldo = ld1; }
  const int r4b = (lane >> 4) * 4;
#pragma unroll
  for (int j = 0; j < 8; j++)
#pragma unroll
    for (int i = 0; i < 4; i++)
#pragma unroll
      for (int r4 = 0; r4 < 4; r4++){
        long row = (long)bm * 256 + (2 * j + wr) * 16 + r4b + r4;
        long col = (long)bn2 * 256 + (4 * i + wc) * 16 + rr;
        long idx = row * ldo + col;
        if (F32OUT) ((float*)op)[idx] = acc[j][i][r4];
        else        ((u16*)op)[idx]  = f2bf(acc[j][i][r4]);
      }
}

// ---------------- dt: LDS-tiled fp32 skinny GEMM (8192x64, K=2048) + softplus + clip ----------------
__global__ __launch_bounds__(256) void dt_kernel(const float* __restrict__ hs, const float* __restrict__ w,
                                                 const float* __restrict__ dt_bias, float* __restrict__ dtp){
  __shared__ float hsS[32][66];
  __shared__ float wS[64][66];
  const int tid = threadIdx.x;
  const int j = tid & 63, rgrp = tid >> 6;
  const long row0 = (long)blockIdx.x * 32;
  const int srow = tid >> 3, sc0 = (tid & 7) * 8;
  const int wrow = tid >> 2, wc0 = (tid & 3) * 16;
  const float* hsg = hs + (row0 + srow) * 2048 + sc0;
  const float* wg  = w + (long)(8448 + wrow) * 2048 + wc0;

  f32x4 acc[8] = {};
  for (int k0 = 0; k0 < 2048; k0 += 64){
    *(f32x4*)&hsS[srow][sc0]     = *(const f32x4*)&hsg[k0];
    *(f32x4*)&hsS[srow][sc0 + 4] = *(const f32x4*)&hsg[k0 + 4];
#pragma unroll
    for (int q = 0; q < 4; q++)
      *(f32x4*)&wS[wrow][wc0 + q * 4] = *(const f32x4*)&wg[k0 + q * 4];
    __syncthreads();
#pragma unroll
    for (int kk = 0; kk < 64; kk += 4){
      f32x4 wv = *(const f32x4*)&wS[j][kk];
#pragma unroll
      for (int r = 0; r < 8; r++){
        f32x4 hv = *(const f32x4*)&hsS[rgrp * 8 + r][kk];
        acc[r] += hv * wv;
      }
    }
    __syncthreads();
  }
  float bias = dt_bias[j];
#pragma unroll
  for (int r = 0; r < 8; r++){
    float x = acc[r][0] + acc[r][1] + acc[r][2] + acc[r][3] + bias;
    float sp = (x > 20.f) ? x : log1pf(expf(x));
    sp = fminf(fmaxf(sp, 0.f), 100.f);
    dtp[(row0 + rgrp * 8 + r) * 64 + j] = sp;
  }
}

// ---------------- per (b,h,chunk): Adt cumsum (fp32) ----------------
__global__ __launch_bounds__(64) void acum_kernel(const float* __restrict__ dtp, const float* __restrict__ A_log,
                                                  float* __restrict__ acum, float* __restrict__ suma){
  int bid = blockIdx.x;                 // ((b*64+h)*16+c)
  int c = bid & 15, h = (bid >> 4) & 63, b = bid >> 10;
  int lane = threadIdx.x;
  float Ah = -expf(A_log[h]);
  long base = ((long)(b * 4096 + c * 256)) * 64 + h;
  float v[4]; float s = 0.f;
#pragma unroll
  for (int i = 0; i < 4; i++){ float adt = dtp[base + (lane * 4 + i) * 64] * Ah; s += adt; v[i] = s; }
  float tot = s, run = s;
  for (int off = 1; off < 64; off <<= 1){ float u = __shfl_up(run, off); if (lane >= off) run += u; }
  float excl = run - tot;
  long ob = (long)bid * 256 + lane * 4;
#pragma unroll
  for (int i = 0; i < 4; i++) acum[ob + i] = excl + v[i];
  if (lane == 63) suma[bid] = run;
}

// ---------------- depthwise conv + bias + silu + split: 4 l-positions/block, 7-row window ----------------
__global__ __launch_bounds__(256) void conv_kernel(const u16* __restrict__ xbc, const float* __restrict__ cw,
                                                   const float* __restrict__ cb,
                                                   u16* __restrict__ xact,
                                                   u16* __restrict__ bmat, u16* __restrict__ cmat){
  int pb = blockIdx.x;                  // b*1024 + l4
  int l0 = (pb & 1023) * 4;
  long pos0 = ((long)(pb >> 10) << 12) + l0;
  for (int cg = threadIdx.x; cg < 544; cg += 256){
    int ch = cg * 8;
    f32x4 cwv[8];
#pragma unroll
    for (int t = 0; t < 8; t++) cwv[t] = *(const f32x4*)&cw[(ch + t) * 4];
    float cbv[8];
#pragma unroll
    for (int t = 0; t < 8; t++) cbv[t] = cb[ch + t];
    bfx8 rr[7];
    bfx8 zz = {};
    rr[0] = (l0 >= 3) ? *(const bfx8*)&xbc[(pos0 - 3) * 4352 + ch] : zz;
    rr[1] = (l0 >= 2) ? *(const bfx8*)&xbc[(pos0 - 2) * 4352 + ch] : zz;
    rr[2] = (l0 >= 1) ? *(const bfx8*)&xbc[(pos0 - 1) * 4352 + ch] : zz;
#pragma unroll
    for (int q = 0; q < 4; q++) rr[3 + q] = *(const bfx8*)&xbc[(pos0 + q) * 4352 + ch];
#pragma unroll
    for (int li = 0; li < 4; li++){
      bfx8 o;
#pragma unroll
      for (int t = 0; t < 8; t++){
        float a = cbv[t] + cwv[t][0] * bf2f((u16)rr[li][t])     + cwv[t][1] * bf2f((u16)rr[li + 1][t])
                         + cwv[t][2] * bf2f((u16)rr[li + 2][t]) + cwv[t][3] * bf2f((u16)rr[li + 3][t]);
        float val = a / (1.f + expf(-a));
        o[t] = (short)f2bf(val);
      }
      long pos = pos0 + li;
      if (ch < 4096)      *(bfx8*)&xact[pos * 4096 + ch] = o;
      else if (ch < 4224) *(bfx8*)&bmat[pos * 128 + ch - 4096] = o;
      else                *(bfx8*)&cmat[pos * 128 + ch - 4224] = o;
    }
  }
}

// ---------------- bmat[b*4096+l][128] -> bmatT[b][n][4096] ----------------
__global__ __launch_bounds__(256) void bt_transpose(const u16* __restrict__ bmat, u16* __restrict__ bmatT){
  __shared__ u16 T[128 * 136];
  int bx = blockIdx.x;                  // b*32 + ltile
  int b = bx >> 5, lt = bx & 31;
  int l0 = lt * 128;
  int tid = threadIdx.x;
  for (int idx = tid; idx < 2048; idx += 256){
    int lrow = idx >> 4, ns = (idx & 15) * 8;
    *(bfx8*)&T[lrow * 136 + ns] = *(const bfx8*)&bmat[((long)b * 4096 + l0 + lrow) * 128 + ns];
  }
  __syncthreads();
  for (int idx = tid; idx < 2048; idx += 256){
    int nrow = idx >> 4, ls = (idx & 15) * 8;
    bfx8 o;
#pragma unroll
    for (int j = 0; j < 8; j++) o[j] = (short)T[(ls + j) * 136 + nrow];
    *(bfx8*)&bmatT[(long)b * 524288 + (long)nrow * 4096 + l0 + ls] = o;
  }
}

// ---------------- per (b,c): G = C @ B^T (256x256, fp32) -- head-independent, computed once ----------------
__global__ __launch_bounds__(256) void cbt_kernel(const u16* __restrict__ cmat, const u16* __restrict__ bmat,
                                                  float* __restrict__ G){
  int bid = blockIdx.x;                 // (b*16+c)*4 + ss
  int ss = bid & 3, bc = bid >> 2;
  int b = bc >> 4, c = bc & 15;
  long rowbase = (long)b * 4096 + c * 256;
  int tid = threadIdx.x, wid = tid >> 6, lane = tid & 63;
  int rr = lane & 15, ko = (lane >> 4) * 8;
  f32x4 acc[4][4] = {};
#pragma unroll
  for (int kk = 0; kk < 4; kk++){
    bfx8 cf[4], bf[4];
#pragma unroll
    for (int lt = 0; lt < 4; lt++) cf[lt] = *(const bfx8*)&cmat[(rowbase + wid * 64 + lt * 16 + rr) * 128 + kk * 32 + ko];
#pragma unroll
    for (int st = 0; st < 4; st++) bf[st] = *(const bfx8*)&bmat[(rowbase + ss * 64 + st * 16 + rr) * 128 + kk * 32 + ko];
#pragma unroll
    for (int lt = 0; lt < 4; lt++)
#pragma unroll
      for (int st = 0; st < 4; st++)
        acc[lt][st] = __builtin_amdgcn_mfma_f32_16x16x32_bf16(cf[lt], bf[st], acc[lt][st], 0, 0, 0);
  }
  long gb2 = (long)bc * 65536;
#pragma unroll
  for (int lt = 0; lt < 4; lt++)
#pragma unroll
    for (int st = 0; st < 4; st++)
#pragma unroll
      for (int r4 = 0; r4 < 4; r4++)
        G[gb2 + (long)(wid * 64 + lt * 16 + (lane >> 4) * 4 + r4) * 256 + ss * 64 + st * 16 + rr] = acc[lt][st][r4];
}

// ---------------- per (b,c,h): chunk end-state E = (X*dt*decay)^T @ B  (bf16 out) ----------------
__global__ __launch_bounds__(256, 4) void states_kernel(const u16* __restrict__ xact, const u16* __restrict__ bmatT,
                                                        const float* __restrict__ acum, const float* __restrict__ suma,
                                                        const float* __restrict__ dtp, u16* __restrict__ stR){
  __shared__ __align__(16) u16 XdT[64 * 264];
  __shared__ float fac[256];
  int bid = blockIdx.x;                 // ((b*16+c)*64+h)
  int h = bid & 63, c = (bid >> 6) & 15, b = bid >> 10;
  int tid = threadIdx.x;
  long rowbase = (long)b * 4096 + c * 256;
  long aco = ((long)((b * 64 + h) * 16 + c)) * 256;
  float sA = suma[(b * 64 + h) * 16 + c];
  fac[tid] = dtp[(rowbase + tid) * 64 + h] * expf(sA - acum[aco + tid]);
  __syncthreads();
  char* xb = (char*)XdT;
  for (int idx = tid; idx < 2048; idx += 256){
    int l = idx >> 3, ps = (idx & 7) * 8;
    int key = (idx & 7) << 4;
    bfx8 xv = *(const bfx8*)&xact[(rowbase + l) * 4096 + h * 64 + ps];
#pragma unroll
    for (int j = 0; j < 8; j++)
      *(u16*)(xb + ((((ps + j) * 264 + l) * 2) ^ key)) = f2bf(bf2f((u16)xv[j]) * fac[l]);
  }
  __syncthreads();
  int wid = tid >> 6, lane = tid & 63;
  int rr = lane & 15, ko = (lane >> 4) * 8;
  const u16* btb = bmatT + (long)b * 524288 + c * 256;
  const int arow = wid * 16 + rr;
  const int akey = ((arow >> 3) & 7) << 4;
  f32x4 acc[8] = {};
#pragma unroll
  for (int ks = 0; ks < 8; ks++){
    bfx8 a = *(const bfx8*)(xb + (((arow * 264 + ks * 32 + ko) * 2) ^ akey));
#pragma unroll
    for (int nt = 0; nt < 8; nt++){
      bfx8 bb = *(const bfx8*)&btb[(long)(nt * 16 + rr) * 4096 + ks * 32 + ko];
      acc[nt] = __builtin_amdgcn_mfma_f32_16x16x32_bf16(a, bb, acc[nt], 0, 0, 0);
    }
  }
  long ob = (long)bid * 8192;
#pragma unroll
  for (int nt = 0; nt < 8; nt++)
#pragma unroll
    for (int r4 = 0; r4 < 4; r4++){
      int p = wid * 16 + (lane >> 4) * 4 + r4;
      stR[ob + p * 128 + nt * 16 + rr] = f2bf(acc[nt][r4]);
    }
}

// ---------------- inter-chunk scan: in-place E -> R (prev_states), bf16; 1024 blocks ----------------
__global__ __launch_bounds__(256) void scan_kernel(u16* stR, const float* __restrict__ suma){
  int g = blockIdx.x;                   // ((b*64+h)*8 + slice)
  int s = g & 7, bh = g >> 3;
  int b = bh >> 6, h = bh & 63;
  int tid = threadIdx.x;
  long off0 = (long)s * 1024 + tid * 4;
  f32x4 R = {};
  for (int c = 0; c < 16; c++){
    long base = ((long)((b * 16 + c) * 64 + h)) * 8192 + off0;
    float sc = expf(suma[(b * 64 + h) * 16 + c]);
    u16x4 e4 = *(const u16x4*)&stR[base];
    u16x4 o = { f2bf(R[0]), f2bf(R[1]), f2bf(R[2]), f2bf(R[3]) };
    *(u16x4*)&stR[base] = o;
#pragma unroll
    for (int t = 0; t < 4; t++) R[t] = sc * R[t] + bf2f(e4[t]);
  }
}

// ---------------- per (b,c,h): Y = (G ∘ L) @ Xdt + exp(Acum)*(C @ R^T) + x*D ----------------
// Wave w owns strips {w, 7-w} (32 rows each): balanced causal work (18 lt-sp units per
// wave vs 8..32 in the contiguous mapping -- critical path 32 -> 18).
__global__ __launch_bounds__(256, 4) void ydiag_kernel(const u16* __restrict__ cmat, const float* __restrict__ G,
                                                       const u16* xact,
                                                       const u16* __restrict__ rbuf, const float* __restrict__ acum,
                                                       const float* __restrict__ dtp,
                                                       const float* __restrict__ Dv, u16* ybuf){
  __shared__ __align__(16) u16 XdTq[64 * 72];
  __shared__ float acL[256];
  __shared__ float dtl[256];
  int bid = blockIdx.x;                 // ((b*16+c)*64+h)
  int h = bid & 63, c = (bid >> 6) & 15, b = bid >> 10;
  int tid = threadIdx.x, wid = tid >> 6, lane = tid & 63;
  long rowbase = (long)b * 4096 + c * 256;
  long aco = ((long)((b * 64 + h) * 16 + c)) * 256;
  acL[tid] = acum[aco + tid];
  dtl[tid] = dtp[(rowbase + tid) * 64 + h];
  __syncthreads();

  int rr = lane & 15, ko = (lane >> 4) * 8;
  int lrow0[4];
#pragma unroll
  for (int lt = 0; lt < 4; lt++)
    lrow0[lt] = (lt < 2) ? (32 * wid + lt * 16) : (32 * (7 - wid) + (lt - 2) * 16);

  f32x4 acc[4][4] = {};

  // Y_off = C @ R^T, scaled by exp(acum[l])
  long rb = (long)bid * 8192;
#pragma unroll
  for (int kk = 0; kk < 4; kk++){
    bfx8 cf[4];
#pragma unroll
    for (int lt = 0; lt < 4; lt++)
      cf[lt] = *(const bfx8*)&cmat[(rowbase + lrow0[lt] + rr) * 128 + kk * 32 + ko];
#pragma unroll
    for (int pt = 0; pt < 4; pt++){
      bfx8 bb = *(const bfx8*)&rbuf[rb + (pt * 16 + rr) * 128 + kk * 32 + ko];
#pragma unroll
      for (int lt = 0; lt < 4; lt++) acc[lt][pt] = __builtin_amdgcn_mfma_f32_16x16x32_bf16(cf[lt], bb, acc[lt][pt], 0, 0, 0);
    }
  }
#pragma unroll
  for (int lt = 0; lt < 4; lt++)
#pragma unroll
    for (int r4 = 0; r4 < 4; r4++){
      float e = expf(acL[lrow0[lt] + (lane >> 4) * 4 + r4]);
#pragma unroll
      for (int pt = 0; pt < 4; pt++) acc[lt][pt][r4] *= e;
    }

  char* xqb = (char*)XdTq;
  const long gb2 = (long)((b * 16 + c)) * 65536;
  for (int q = 0; q < 4; q++){
    __syncthreads();
    for (int idx = tid; idx < 512; idx += 256){
      int lq = idx >> 3, ps = (idx & 7) * 8;
      int key = (idx & 7) << 4;
      int l = q * 64 + lq;
      bfx8 xv = *(const bfx8*)&xact[(rowbase + l) * 4096 + h * 64 + ps];
#pragma unroll
      for (int j = 0; j < 8; j++)
        *(u16*)(xqb + ((((ps + j) * 72 + lq) * 2) ^ key)) = f2bf(bf2f((u16)xv[j]) * dtl[l]);
    }
    __syncthreads();
#pragma unroll
    for (int sub = 0; sub < 2; sub++){
      int sp = q * 2 + sub;
      bool doA = (sp <= wid), doB = (sp <= 7 - wid);   // wave-uniform
      if (!doA && !doB) continue;
      int s0 = sp * 32;
#pragma unroll
      for (int lt = 0; lt < 4; lt++){
        if (lt < 2 ? !doA : !doB) continue;
        int lrow = lrow0[lt] + rr;
        float eL = acL[lrow];
        f32x4 g0 = *(const f32x4*)&G[gb2 + (long)lrow * 256 + s0 + ko];
        f32x4 g1 = *(const f32x4*)&G[gb2 + (long)lrow * 256 + s0 + ko + 4];
        bfx8 a1;
#pragma unroll
        for (int j = 0; j < 4; j++){
          int s = s0 + ko + j;
          float sc = (s <= lrow) ? expf(eL - acL[s]) : 0.f;
          a1[j] = (short)f2bf(g0[j] * sc);
        }
#pragma unroll
        for (int j = 0; j < 4; j++){
          int s = s0 + ko + 4 + j;
          float sc = (s <= lrow) ? expf(eL - acL[s]) : 0.f;
          a1[4 + j] = (short)f2bf(g1[j] * sc);
        }
#pragma unroll
        for (int pt = 0; pt < 4; pt++){
          int prow = pt * 16 + rr;
          bfx8 bb = *(const bfx8*)(xqb + (((prow * 72 + sub * 32 + ko) * 2) ^ (((prow >> 3) & 7) << 4)));
          acc[lt][pt] = __builtin_amdgcn_mfma_f32_16x16x32_bf16(a1, bb, acc[lt][pt], 0, 0, 0);
        }
      }
    }
  }
  float Dh = Dv[h];
#pragma unroll
  for (int lt = 0; lt < 4; lt++)
#pragma unroll
    for (int pt = 0; pt < 4; pt++)
#pragma unroll
      for (int r4 = 0; r4 < 4; r4++){
        int lrow = lrow0[lt] + (lane >> 4) * 4 + r4;
        int pcol = pt * 16 + rr;
        long gi = (rowbase + lrow) * 4096 + h * 64 + pcol;
        ybuf[gi] = f2bf(acc[lt][pt][r4] + bf2f(xact[gi]) * Dh);
      }
}

// ---------------- RMSNorm + silu(z) gate (may write in place over ybuf) ----------------
__global__ __launch_bounds__(256) void rms_kernel(const u16* ybuf, const u16* zbuf,
                                                  const float* __restrict__ norm_w, u16* ynorm){
  __shared__ float red[4];
  long row = blockIdx.x;
  int tid = threadIdx.x;
  long yb = row * 4096 + tid * 16;
  bfx8 v0 = *(const bfx8*)&ybuf[yb];
  bfx8 v1 = *(const bfx8*)&ybuf[yb + 8];
  float vals[16];
#pragma unroll
  for (int t = 0; t < 8; t++){ vals[t] = bf2f((u16)v0[t]); vals[8 + t] = bf2f((u16)v1[t]); }
  float ss = 0.f;
#pragma unroll
  for (int t = 0; t < 16; t++) ss += vals[t] * vals[t];
#pragma unroll
  for (int off = 32; off >= 1; off >>= 1) ss += __shfl_xor(ss, off);
  if ((tid & 63) == 0) red[tid >> 6] = ss;
  __syncthreads();
  float rs = rsqrtf((red[0] + red[1] + red[2] + red[3]) * (1.f / 4096.f) + 1e-5f);
  bfx8 z0 = *(const bfx8*)&zbuf[yb];
  bfx8 z1 = *(const bfx8*)&zbuf[yb + 8];
  bfx8 o0, o1;
#pragma unroll
  for (int t = 0; t < 16; t++){
    float zv = bf2f((u16)(t < 8 ? z0[t] : z1[t - 8]));
    float g = zv / (1.f + expf(-zv));
    u16 r = f2bf(vals[t] * rs * norm_w[tid * 16 + t] * g);
    if (t < 8) o0[t] = (short)r; else o1[t - 8] = (short)r;
  }
  *(bfx8*)&ynorm[yb] = o0;
  *(bfx8*)&ynorm[yb + 8] = o1;
}

extern "C" void kernel_launch(void* const* d_in, const int* in_sizes, int n_in,
                              void* d_out, int out_size, void* d_ws, size_t ws_size,
                              hipStream_t stream){
  const float* hs   = (const float*)d_in[0];
  const float* inw  = (const float*)d_in[1];
  const float* cw   = (const float*)d_in[2];
  const float* cb   = (const float*)d_in[3];
  const float* dtb  = (const float*)d_in[4];
  const float* alog = (const float*)d_in[5];
  const float* Dv   = (const float*)d_in[6];
  const float* nw   = (const float*)d_in[7];
  const float* outw = (const float*)d_in[8];

  const size_t REQ = 147857408ULL;
  if (ws_size < REQ){
    hipMemsetAsync(d_out, 0x42, (size_t)out_size * 4, stream);
    return;
  }
  char* ws = (char*)d_ws;
  u16*   hsb  = (u16*)  (ws + 0L);             // 33,554,432   (dead after gemm1)
  u16*   wbi  = (u16*)  (ws + 33554432L);      // 34,603,008   (dead after gemm1)
  u16*   xbc  = (u16*)  (ws + 68157440L);      // 71,303,168   (dead after conv)
  u16*   xact = (u16*)  (ws + 0L);             // 67,108,864   (overlays hsb+wbi; = ybuf = ynorm)
  u16*   stR  = (u16*)  (ws + 68157440L);      // 33,554,432   (overlays xbc)
  u16*   wbo  = (u16*)  (ws + 101711872L);     // 16,777,216   (overlays xbc)
  u16*   bmatT= (u16*)  (ws + 118489088L);     //  2,097,152   (overlays xbc)
  float* Gbuf = (float*)(ws + 120586240L);     //  8,388,608   (overlays xbc tail; ends 128,974,848)
  float* dtp  = (float*)(ws + 139460608L);     //  2,097,152
  float* acum = (float*)(ws + 141557760L);     //  2,097,152
  float* suma = (float*)(ws + 143654912L);     //      8,192
  u16*   bmat = (u16*)  (ws + 143663104L);     //  2,097,152
  u16*   cmat = (u16*)  (ws + 145760256L);     //  2,097,152  (end = 147,857,408)
  u16*   zbuf = (u16*)  d_out;                 // 67,108,864 = exactly out_size*4

  cvt2_kernel<<<33280, 256, 0, stream>>>(hs, hsb, 4194304, inw, wbi, 4325376);
  gemm256<0><<<dim3(32, 33), 512, 0, stream>>>(hsb, wbi, zbuf, xbc, 2048, 4096, 4352, 16);
  dt_kernel<<<256, 256, 0, stream>>>(hs, inw, dtb, dtp);
  acum_kernel<<<2048, 64, 0, stream>>>(dtp, alog, acum, suma);
  conv_kernel<<<2048, 256, 0, stream>>>(xbc, cw, cb, xact, bmat, cmat);    // xact over dead hsb+wbi
  cvt_kernel<<<8192, 256, 0, stream>>>(outw, wbo, 2097152);                // wbo over dead xbc
  bt_transpose<<<64, 256, 0, stream>>>(bmat, bmatT);
  cbt_kernel<<<128, 256, 0, stream>>>(cmat, bmat, Gbuf);                   // G = C@B^T per (b,c)
  states_kernel<<<2048, 256, 0, stream>>>(xact, bmatT, acum, suma, dtp, stR);
  scan_kernel<<<1024, 256, 0, stream>>>(stR, suma);
  ydiag_kernel<<<2048, 256, 0, stream>>>(cmat, Gbuf, xact, stR, acum, dtp, Dv, xact);  // in-place Y
  rms_kernel<<<8192, 256, 0, stream>>>(xact, zbuf, nw, xact);                           // in-place norm
  gemm256<1><<<dim3(32, 8), 512, 0, stream>>>(xact, wbo, d_out, d_out, 4096, 2048, 2048, 999);
}